// Round 23
// baseline (461.608 us; speedup 1.0000x reference)
//
#include <hip/hip_runtime.h>
#include <hip/hip_bf16.h>
#include <stdint.h>

// LSTM-CRF forward loss. B=128 L=256 V=6000 E=128 RV=300 RD=100 H=256 C=33
// DIN=428 (pad to 512 fp8). Pipeline:
//   pack_all (W8/A8 fp8 pre-swizzled, Whh MX frags, bias, Wcls)
//   -> gemm_xg (MX K=128 fp8, pair-contiguous X2)
//   -> lstm_recur (128 wg; MX K=128; 1 output/lane)  [r20/r22, proven 243us]
//   -> crf3_k (emission GEMM fused into CRF scan; E in LDS) -> fin_k

typedef unsigned short u16;
typedef __attribute__((ext_vector_type(8))) __bf16 bf16x8;
typedef __attribute__((ext_vector_type(4))) float f32x4;
typedef __attribute__((ext_vector_type(8))) int i32x8;
typedef __attribute__((ext_vector_type(4))) int i32x4;

struct __align__(8) u16x4 { u16 x, y, z, w; };

typedef const void __attribute__((address_space(1))) gas_t;
typedef void __attribute__((address_space(3))) las_t;

static __device__ __forceinline__ void gload16(const void* g, void* l) {
  __builtin_amdgcn_global_load_lds((gas_t*)g, (las_t*)l, 16, 0, 0);
}

static __device__ __forceinline__ u16 f2b(float x) {
  uint32_t u = __builtin_bit_cast(uint32_t, x);
  uint32_t r = u + 0x7fffu + ((u >> 16) & 1u);
  return (u16)(r >> 16);
}
static __device__ __forceinline__ float b2lo(uint32_t u) {
  return __builtin_bit_cast(float, u << 16);
}
static __device__ __forceinline__ float b2hi(uint32_t u) {
  return __builtin_bit_cast(float, u & 0xffff0000u);
}
static __device__ __forceinline__ uint32_t pkbf16(float lo, float hi) {
  uint32_t w;
  asm("v_cvt_pk_bf16_f32 %0, %1, %2" : "=v"(w) : "v"(lo), "v"(hi));
  return w;
}
static __device__ __forceinline__ uint32_t pkf8x4(float x, float y, float z, float w) {
  unsigned int r01 = __builtin_amdgcn_cvt_pk_fp8_f32(x, y, 0u, false) & 0xffffu;
  unsigned int r23 = __builtin_amdgcn_cvt_pk_fp8_f32(z, w, 0u, false) & 0xffffu;
  return r01 | (r23 << 16);
}
static __device__ __forceinline__ float sigf(float x) {
  return __builtin_amdgcn_rcpf(1.f + __expf(-x));
}
static __device__ __forceinline__ float tanh_(float x) {
  return 1.f - 2.f * __builtin_amdgcn_rcpf(1.f + __expf(2.f * x));
}
static __device__ __forceinline__ f32x4 MFMA(bf16x8 a, bf16x8 b, f32x4 c) {
  return __builtin_amdgcn_mfma_f32_16x16x32_bf16(a, b, c, 0, 0, 0);
}

// ---------------- pack_all ----------------
// W8 [2048][512] fp8, swizzled c^=(r&7)<<4; bias 2048 f32; WclsP [48][512] bf16;
// WhhF8 MX frags (131072 dwords, r20 layout); A8 [32768][512] fp8, swizzled.
__global__ __launch_bounds__(256) void pack_all(
    const float* __restrict__ Wih_f, const float* __restrict__ Wih_b,
    const float* __restrict__ Whh_f, const float* __restrict__ Whh_b,
    const float* __restrict__ bih_f, const float* __restrict__ bhh_f,
    const float* __restrict__ bih_b, const float* __restrict__ bhh_b,
    const float* __restrict__ Wcls,
    const int* __restrict__ data, const int* __restrict__ onerad,
    const float* __restrict__ embed, const float* __restrict__ rad,
    unsigned char* __restrict__ W8, unsigned int* __restrict__ WhhF8,
    float* __restrict__ biasP, u16* __restrict__ WclsP,
    unsigned char* __restrict__ A8) {
  if (blockIdx.x < 1640) {
    int idx = blockIdx.x * 256 + threadIdx.x;
    if (idx < 262144) {                       // W8: 2048 rows x 128 chunks
      int r = idx >> 7, c7 = idx & 127, k0 = c7 * 4;
      int d = r >> 10, rr = r & 1023;
      const float* W = d ? Wih_b : Wih_f;
      float4 f;
      if (k0 < 428) f = *(const float4*)(W + (size_t)rr * 428 + k0);
      else          f = make_float4(0.f, 0.f, 0.f, 0.f);
      *(unsigned int*)(W8 + (size_t)r * 512 + (k0 ^ ((r & 7) << 4))) =
          pkf8x4(f.x, f.y, f.z, f.w);
    } else if (idx < 264192) {                // bias 2048
      int j = idx - 262144;
      int r = j & 1023;
      biasP[j] = (j >> 10) ? (bih_b[r] + bhh_b[r]) : (bih_f[r] + bhh_f[r]);
    } else if (idx < 288768) {                // Wcls 48*512
      int j = idx - 264192;
      int r = j >> 9, k = j & 511;
      WclsP[j] = (r < 33) ? f2b(Wcls[r * 512 + k]) : (u16)0;
    } else if (idx < 419840) {                // WhhF8: 131072 dwords (MX frags)
      int q = idx - 288768;
      int f = q >> 9;                 // frag 0..255
      int kt = f & 1, u = (f >> 1) & 7, v = (f >> 4) & 7, dd = f >> 7;
      int w9 = q & 511;
      int lane = w9 >> 3;
      int eb = (w9 & 7) * 4;
      int gate = u >> 1, jf = u & 1;
      int gcol = gate * 256 + v * 32 + jf * 16 + (lane & 15);
      int k = kt * 128 + (lane >> 4) * 32 + eb;
      const float* W = dd ? Whh_b : Whh_f;
      float4 fv4 = *(const float4*)(W + (size_t)gcol * 256 + k);
      WhhF8[q] = pkf8x4(fv4.x, fv4.y, fv4.z, fv4.w);
    }
  } else {
    int idx = (blockIdx.x - 1640) * 256 + threadIdx.x;  // 32768*128 chunks
    int m = idx >> 7, c = idx & 127, k0 = c * 4;
    float4 vv;
    if (k0 < 128)      vv = *(const float4*)(embed + (size_t)data[m] * 128 + k0);
    else if (k0 < 228) vv = *(const float4*)(rad + (size_t)onerad[m] * 100 + (k0 - 128));
    else if (k0 < 328) vv = *(const float4*)(rad + (size_t)onerad[32768 + m] * 100 + (k0 - 228));
    else if (k0 < 428) vv = *(const float4*)(rad + (size_t)onerad[65536 + m] * 100 + (k0 - 328));
    else               vv = make_float4(0.f, 0.f, 0.f, 0.f);
    *(unsigned int*)(A8 + (size_t)m * 512 + (k0 ^ ((m & 7) << 4))) =
        pkf8x4(vv.x, vv.y, vv.z, vv.w);
  }
}

// ---------------- xg GEMM (MX fp8): X2 = pair-contiguous(A @ Wih^T + bias) ----------------
// 128x128 tile, BK=128, 4 waves (2x2 of 64x64), 64 mfma_scale_16x16x128/wave.
// Staging: o = ps*4096 + tid*16 (LDS dest wave-uniform + lane*16).
// X2 u16 layout per d (33554432 u16): idx = R*1024 + gate*256 + v*32 + l16*2 + jf.
#define GXM(i, j) \
  acc[i][j] = __builtin_amdgcn_mfma_scale_f32_16x16x128_f8f6f4( \
      af[i], bfj, acc[i][j], 0, 0, 0, 0x7F7F7F7Fu, 0, 0x7F7F7F7Fu);
__global__ __launch_bounds__(256, 2) void gemm_xg(const unsigned char* __restrict__ A8,
    const unsigned char* __restrict__ W8, const float* __restrict__ bias,
    u16* __restrict__ X2) {
  __shared__ unsigned char As[16384];   // [128][128]
  __shared__ unsigned char Bs[16384];
  int bid = blockIdx.x;
  int mt = bid >> 4, nt = bid & 15;
  int m0 = mt * 128, n0 = nt * 128;
  int tid = threadIdx.x;
  int w = tid >> 6, lane = tid & 63, l16 = lane & 15;
  int wr = w >> 1, wc = w & 1;
  int kc0 = (lane >> 4) * 32;
  f32x4 zero4 = {0.f, 0.f, 0.f, 0.f};
  f32x4 acc[4][4];
#pragma unroll
  for (int i = 0; i < 4; ++i)
#pragma unroll
    for (int j = 0; j < 4; ++j) acc[i][j] = zero4;
  for (int kk = 0; kk < 4; ++kk) {
    int kb = kk * 128;
#pragma unroll
    for (int ps = 0; ps < 4; ++ps) {
      int o = ps * 4096 + tid * 16;       // LDS dest: wave-uniform + lane*16
      int rs = o >> 7, cb = o & 127;      // global src: per-lane
      gload16(A8 + (size_t)(m0 + rs) * 512 + kb + cb, (char*)As + o);
      gload16(W8 + (size_t)(n0 + rs) * 512 + kb + cb, (char*)Bs + o);
    }
    __syncthreads();
    i32x8 af[4];
#pragma unroll
    for (int i = 0; i < 4; ++i) {
      int arow = wr * 64 + i * 16 + l16;
      int sw = (arow & 7) << 4;
      const unsigned char* ab = As + arow * 128;
      i32x4 x0 = *(const i32x4*)(ab + (kc0 ^ sw));
      i32x4 x1 = *(const i32x4*)(ab + ((kc0 + 16) ^ sw));
      af[i] = (i32x8){x0[0], x0[1], x0[2], x0[3], x1[0], x1[1], x1[2], x1[3]};
    }
#pragma unroll
    for (int j = 0; j < 4; ++j) {
      int brow = wc * 64 + j * 16 + l16;
      int sw = (brow & 7) << 4;
      const unsigned char* bb = Bs + brow * 128;
      i32x4 y0 = *(const i32x4*)(bb + (kc0 ^ sw));
      i32x4 y1 = *(const i32x4*)(bb + ((kc0 + 16) ^ sw));
      i32x8 bfj = (i32x8){y0[0], y0[1], y0[2], y0[3], y1[0], y1[1], y1[2], y1[3]};
      GXM(0, j) GXM(1, j) GXM(2, j) GXM(3, j)
    }
    __syncthreads();
  }
  float bv[4];
#pragma unroll
  for (int j = 0; j < 4; ++j) bv[j] = bias[n0 + wc * 64 + j * 16 + l16];
  int dd = n0 >> 10;
  int g = lane >> 4;
#pragma unroll
  for (int i = 0; i < 4; ++i)
#pragma unroll
    for (int jp = 0; jp < 2; ++jp) {
      int j0 = jp * 2;
      int c = (n0 + wc * 64 + j0 * 16 + l16) & 1023;   // jf=0 member
      int gate = c >> 8, vv = (c >> 5) & 7, lc = c & 15;
      size_t base = (size_t)dd * 33554432 + (size_t)gate * 256 + vv * 32 + lc * 2;
#pragma unroll
      for (int r = 0; r < 4; ++r) {
        int row = m0 + wr * 64 + i * 16 + g * 4 + r;
        *(unsigned int*)(X2 + base + (size_t)row * 1024) =
            pkbf16(acc[i][j0][r] + bv[j0], acc[i][j0 + 1][r] + bv[j0 + 1]);
      }
    }
}

// ---------------- LSTM recurrence: 128 blocks, 2-row chunks, MX K=128 MFMA ----------------
// r20/r22, proven 243us. Wave v owns gate-cols {gate*256+v*32+jf*16+[0,16)}
// (u = gate*2+jf, 8 tiles), K=256 as 2 x K=128 scaled MFMAs per tile ->
// 16 MFMA/wave/step. Whh in 16 i32x8 register frags. h in LDS [16][256] fp8
// XOR-swizzled; lane owns ONE output (row = lane>>5, col = v*32+jf*16+l16).
#define MXM(u, Af, Bf) \
  acc[u] = __builtin_amdgcn_mfma_scale_f32_16x16x128_f8f6f4( \
      Af, Bf, acc[u], 0, 0, 0, 0x7F7F7F7Fu, 0, 0x7F7F7F7Fu);
#define GVAL(gate, dst) { \
  float a00 = __shfl(acc[(gate) * 2][0],     srcl); \
  float a01 = __shfl(acc[(gate) * 2][1],     srcl); \
  float a10 = __shfl(acc[(gate) * 2 + 1][0], srcl); \
  float a11 = __shfl(acc[(gate) * 2 + 1][1], srcl); \
  float s0 = hirow ? a01 : a00; \
  float s1 = hirow ? a11 : a10; \
  float xv = hijf ? b2hi(pxA[gate]) : b2lo(pxA[gate]); \
  dst = (hijf ? s1 : s0) + xv; }
#define FENCE { __builtin_amdgcn_sched_barrier(0); \
  asm volatile("s_waitcnt lgkmcnt(0)"); \
  __builtin_amdgcn_s_barrier(); \
  __builtin_amdgcn_sched_barrier(0); }

__global__ __launch_bounds__(512, 1) void lstm_recur(const u16* __restrict__ xg,
    const unsigned char* __restrict__ WhhF8, u16* __restrict__ outh) {
  __shared__ unsigned char hfA[2][4096];   // [16 rows][256 k] fp8, XOR-swizzled
  int blk = blockIdx.x;
  int d = blk >> 6, ch = blk & 63;
  int rowA0 = ch * 2;
  int tid = threadIdx.x;
  int v = tid >> 6, lane = tid & 63, l16 = lane & 15;
  int row = lane >> 5;           // output row 0/1
  int jf = (lane >> 4) & 1;
  bool hirow = (row == 1), hijf = (jf == 1);
  int srcl = l16;
  int col = v * 32 + jf * 16 + l16;

  const char* wb = (const char*)WhhF8 + (size_t)(d * 8 + v) * 32768 + (size_t)lane * 32;
  i32x8 bf0  = *(const i32x8*)(wb);
  i32x8 bf1  = *(const i32x8*)(wb + 2048);
  i32x8 bf2  = *(const i32x8*)(wb + 4096);
  i32x8 bf3  = *(const i32x8*)(wb + 6144);
  i32x8 bf4  = *(const i32x8*)(wb + 8192);
  i32x8 bf5  = *(const i32x8*)(wb + 10240);
  i32x8 bf6  = *(const i32x8*)(wb + 12288);
  i32x8 bf7  = *(const i32x8*)(wb + 14336);
  i32x8 bf8  = *(const i32x8*)(wb + 16384);
  i32x8 bf9  = *(const i32x8*)(wb + 18432);
  i32x8 bf10 = *(const i32x8*)(wb + 20480);
  i32x8 bf11 = *(const i32x8*)(wb + 22528);
  i32x8 bf12 = *(const i32x8*)(wb + 24576);
  i32x8 bf13 = *(const i32x8*)(wb + 26624);
  i32x8 bf14 = *(const i32x8*)(wb + 28672);
  i32x8 bf15 = *(const i32x8*)(wb + 30720);
  asm volatile("" :: "v"(bf0), "v"(bf1), "v"(bf2), "v"(bf3), "v"(bf4),
               "v"(bf5), "v"(bf6), "v"(bf7), "v"(bf8), "v"(bf9), "v"(bf10),
               "v"(bf11), "v"(bf12), "v"(bf13), "v"(bf14), "v"(bf15));

  for (int i = tid; i < 2048; i += 512) ((int*)hfA)[i] = 0;

  int arow = lane & 15;
  int sw = (arow & 7) << 4;
  int kb = (lane >> 4) * 32;
  int o0 = arow * 256 + ((kb) ^ sw);
  int o1 = arow * 256 + ((kb + 16) ^ sw);
  int o2 = arow * 256 + ((kb + 128) ^ sw);
  int o3 = arow * 256 + ((kb + 144) ^ sw);

  int t0 = d ? 255 : 0;
  int tpx = d ? -2048 : 2048;    // bytes per t-step in X2 (1024 u16/row-step)
  int tob = d ? -1024 : 1024;    // bytes per t-step in outh (512 u16)

  const char* pb = (const char*)xg + (size_t)d * 67108864
      + ((size_t)(rowA0 + row) * 256 + t0) * 2048 + v * 64 + l16 * 4;
  char* sb = (char*)outh
      + (((size_t)(rowA0 + row) * 256 + t0) * 512 + d * 256 + col) * 2;
  int fwoff = row * 256 + (col ^ (row << 4));   // row&7 == row (0/1)

  unsigned int pxA[4];
  pxA[0] = *(const unsigned int*)(pb);
  pxA[1] = *(const unsigned int*)(pb + 512);
  pxA[2] = *(const unsigned int*)(pb + 1024);
  pxA[3] = *(const unsigned int*)(pb + 1536);

  asm volatile("s_waitcnt vmcnt(0)" ::: "memory");
  __builtin_amdgcn_sched_barrier(0);

  f32x4 zero4 = {0.f, 0.f, 0.f, 0.f};
  float cst = 0.f;
  f32x4 acc[8];
  __syncthreads();

#pragma unroll 1
  for (int tt = 0; tt < 256; ++tt) {
    int p = tt & 1;
    {
      const unsigned char* hb = &hfA[p][0];
      i32x4 a0 = *(const i32x4*)(hb + o0);
      i32x4 a1 = *(const i32x4*)(hb + o1);
      i32x4 a2 = *(const i32x4*)(hb + o2);
      i32x4 a3 = *(const i32x4*)(hb + o3);
      asm volatile("s_waitcnt lgkmcnt(0)");
      __builtin_amdgcn_sched_barrier(0);
      i32x8 A0 = {a0[0], a0[1], a0[2], a0[3], a1[0], a1[1], a1[2], a1[3]};
      i32x8 A1 = {a2[0], a2[1], a2[2], a2[3], a3[0], a3[1], a3[2], a3[3]};
      acc[0] = zero4; acc[1] = zero4; acc[2] = zero4; acc[3] = zero4;
      acc[4] = zero4; acc[5] = zero4; acc[6] = zero4; acc[7] = zero4;
      __builtin_amdgcn_s_setprio(1);
      MXM(0, A0, bf0)  MXM(1, A0, bf2)  MXM(2, A0, bf4)  MXM(3, A0, bf6)
      MXM(4, A0, bf8)  MXM(5, A0, bf10) MXM(6, A0, bf12) MXM(7, A0, bf14)
      MXM(0, A1, bf1)  MXM(1, A1, bf3)  MXM(2, A1, bf5)  MXM(3, A1, bf7)
      MXM(4, A1, bf9)  MXM(5, A1, bf11) MXM(6, A1, bf13) MXM(7, A1, bf15)
      __builtin_amdgcn_s_setprio(0);
    }
    {
      float iv, fv, gv, ov;
      GVAL(0, iv) GVAL(1, fv) GVAL(2, gv) GVAL(3, ov)
      float cn = sigf(fv) * cst + sigf(iv) * tanh_(gv);
      cst = cn;
      float hv = sigf(ov) * tanh_(cn);
      hfA[p ^ 1][fwoff] =
          (unsigned char)__builtin_amdgcn_cvt_pk_fp8_f32(hv, hv, 0u, false);
      *(u16*)sb = f2b(hv);
    }
    sb += tob; pb += tpx;
    pxA[0] = *(const unsigned int*)(pb);
    pxA[1] = *(const unsigned int*)(pb + 512);
    pxA[2] = *(const unsigned int*)(pb + 1024);
    pxA[3] = *(const unsigned int*)(pb + 1536);
    FENCE;
  }
}

// ---------------- crf3: emission GEMM + golden + CRF scan, fused ----------------
// 128 blocks x 256 thr. Phase 1: E[256][33] = outh_rows @ Wcls^T + bcls via
// bf16 MFMA (4 waves x 64 rows each), written straight to LDS. Phase 2:
// wave 0 computes golden + forward logsumexp scan (all threads hit barriers).
__global__ __launch_bounds__(256) void crf3_k(const int* __restrict__ tag,
    const u16* __restrict__ outh, const u16* __restrict__ WclsP,
    const float* __restrict__ bcls, const float* __restrict__ T,
    float* __restrict__ part) {
  __shared__ float Ts[1089];
  __shared__ float E[8448];
  __shared__ float sc[33];
  __shared__ int   lenS;
  __shared__ float gS;
  int b = blockIdx.x;
  int tid = threadIdx.x;
  int w = tid >> 6, lane = tid & 63, l16 = lane & 15, g = lane >> 4;
  for (int i = tid; i < 1089; i += 256) Ts[i] = T[i];
  // ---- emission GEMM into E ----
  {
    f32x4 zero4 = {0.f, 0.f, 0.f, 0.f};
    f32x4 acc[4][3];
#pragma unroll
    for (int mf = 0; mf < 4; ++mf)
#pragma unroll
      for (int nf = 0; nf < 3; ++nf) acc[mf][nf] = zero4;
    int mbase = b * 256 + w * 64;
#pragma unroll 1
    for (int kf = 0; kf < 16; ++kf) {
      bf16x8 bb[3];
#pragma unroll
      for (int nf = 0; nf < 3; ++nf)
        bb[nf] = *(const bf16x8*)(WclsP + (size_t)(nf * 16 + l16) * 512 + kf * 32 + g * 8);
#pragma unroll
      for (int mf = 0; mf < 4; ++mf) {
        bf16x8 a = *(const bf16x8*)(outh
            + (size_t)(mbase + mf * 16 + l16) * 512 + kf * 32 + g * 8);
#pragma unroll
        for (int nf = 0; nf < 3; ++nf) acc[mf][nf] = MFMA(a, bb[nf], acc[mf][nf]);
      }
    }
#pragma unroll
    for (int nf = 0; nf < 3; ++nf) {
      int c = nf * 16 + l16;
      if (c < 33) {
        float bc = bcls[c];
#pragma unroll
        for (int mf = 0; mf < 4; ++mf)
#pragma unroll
          for (int r = 0; r < 4; ++r)
            E[(w * 64 + mf * 16 + g * 4 + r) * 33 + c] = acc[mf][nf][r] + bc;
      }
    }
  }
  // ---- len + golden (wave 0) ----
  if (w == 0) {
    int cnt = 0;
    for (int i = lane; i < 256; i += 64) cnt += (tag[b * 256 + i] != 0) ? 1 : 0;
#pragma unroll
    for (int o = 1; o < 64; o <<= 1) cnt += __shfl_xor(cnt, o);
    if (lane == 0) lenS = cnt;
  }
  __syncthreads();   // E + Ts + lenS visible
  if (w == 0) {
    float gval = 0.f;
    for (int l = lane; l < 256; l += 64) {
      int tg = tag[b * 256 + l];
      if (tg != 0) {
        int prev = (l == 0) ? 31 : tag[b * 256 + l - 1];
        gval += E[l * 33 + tg] + Ts[prev * 33 + tg];
      }
    }
#pragma unroll
    for (int o = 32; o > 0; o >>= 1) gval += __shfl_down(gval, o);
    if (lane == 0) gS = gval;
  }
  // ---- forward scan (all threads participate in barriers) ----
  int c = tid;
  float tcol[33];
  if (c < 33) {
#pragma unroll
    for (int p = 0; p < 33; ++p) tcol[p] = Ts[p * 33 + c];
    sc[c] = E[c] + tcol[31];   // START=31
  }
  __syncthreads();
  int len = lenS;
#pragma unroll 1
  for (int t = 1; t < len; ++t) {
    float nv = 0.f;
    if (c < 33) {
      float ec = E[t * 33 + c];
      float vb[33];
      float m0 = -3.0e38f, m1 = -3.0e38f, m2 = -3.0e38f, m3 = -3.0e38f;
#pragma unroll
      for (int p = 0; p < 32; p += 4) {
        vb[p]     = sc[p]     + tcol[p];     m0 = fmaxf(m0, vb[p]);
        vb[p + 1] = sc[p + 1] + tcol[p + 1]; m1 = fmaxf(m1, vb[p + 1]);
        vb[p + 2] = sc[p + 2] + tcol[p + 2]; m2 = fmaxf(m2, vb[p + 2]);
        vb[p + 3] = sc[p + 3] + tcol[p + 3]; m3 = fmaxf(m3, vb[p + 3]);
      }
      vb[32] = sc[32] + tcol[32];
      float mx = fmaxf(fmaxf(fmaxf(m0, m1), fmaxf(m2, m3)), vb[32]);
      float s0 = 0.f, s1 = 0.f, s2 = 0.f, s3 = 0.f;
#pragma unroll
      for (int p = 0; p < 32; p += 4) {
        s0 += __expf(vb[p] - mx);     s1 += __expf(vb[p + 1] - mx);
        s2 += __expf(vb[p + 2] - mx); s3 += __expf(vb[p + 3] - mx);
      }
      s0 += __expf(vb[32] - mx);
      nv = ec + mx + __logf((s0 + s1) + (s2 + s3));
    }
    __syncthreads();
    if (c < 33) sc[c] = nv;
    __syncthreads();
  }
  if (tid == 0) part[b] = sc[32] - gS;   // END=32
}

// ---------------- finalize: loss = sum(part) / 128 ----------------
__global__ __launch_bounds__(64) void fin_k(const float* __restrict__ part,
    float* __restrict__ out) {
  int l = threadIdx.x;
  float v = part[l] + part[l + 64];
#pragma unroll
  for (int o = 32; o > 0; o >>= 1) v += __shfl_down(v, o);
  if (l == 0) out[0] = v / 128.f;
}

extern "C" void kernel_launch(void* const* d_in, const int* in_sizes, int n_in,
                              void* d_out, int out_size, void* d_ws, size_t ws_size,
                              hipStream_t stream) {
  const int*   batch_data   = (const int*)d_in[0];
  const int*   batch_onerad = (const int*)d_in[1];
  const int*   batch_tag    = (const int*)d_in[2];
  const float* embed        = (const float*)d_in[3];
  const float* rad_embed    = (const float*)d_in[4];
  const float* Wih_f = (const float*)d_in[5];
  const float* Whh_f = (const float*)d_in[6];
  const float* bih_f = (const float*)d_in[7];
  const float* bhh_f = (const float*)d_in[8];
  const float* Wih_b = (const float*)d_in[9];
  const float* Whh_b = (const float*)d_in[10];
  const float* bih_b = (const float*)d_in[11];
  const float* bhh_b = (const float*)d_in[12];
  const float* Wcls  = (const float*)d_in[13];
  const float* bcls  = (const float*)d_in[14];
  const float* trans = (const float*)d_in[15];

  // workspace layout (~203.9 MB)
  char* ws = (char*)d_ws;
  unsigned char* A8 = (unsigned char*)(ws + 0);  // 32768*512 = 16777216
  u16*   X2    = (u16*)  (ws + 29360128);     // 134217728 (pair-contiguous xg)
  unsigned char* W8 = (unsigned char*)(ws + 163577856);  // 2048*512 = 1048576
  unsigned int* WhhF8 = (unsigned int*)(ws + 165412864); // 524288 (MX frags)
  float* biasP = (float*)(ws + 165937152);    // 8192
  u16*   WclsP = (u16*)  (ws + 165945344);    // 49152
  u16*   outh  = (u16*)  (ws + 165994496);    // 33554432
  float* part  = (float*)(ws + 203874304);    // 512

  pack_all<<<18024, 256, 0, stream>>>(Wih_f, Wih_b, Whh_f, Whh_b, bih_f, bhh_f,
                                      bih_b, bhh_b, Wcls, batch_data, batch_onerad,
                                      embed, rad_embed, W8, WhhF8, biasP, WclsP, A8);
  gemm_xg<<<4096, 256, 0, stream>>>(A8, W8, biasP, X2);
  lstm_recur<<<128, 512, 0, stream>>>(X2, (const unsigned char*)WhhF8, outh);
  crf3_k<<<128, 256, 0, stream>>>(batch_tag, outh, WclsP, bcls, trans, part);
  fin_k<<<1, 64, 0, stream>>>(part, (float*)d_out);
}

// Round 24
// 446.869 us; speedup vs baseline: 1.0330x; 1.0330x over previous
//
#include <hip/hip_runtime.h>
#include <hip/hip_bf16.h>
#include <stdint.h>

// LSTM-CRF forward loss. B=128 L=256 V=6000 E=128 RV=300 RD=100 H=256 C=33
// DIN=428 (pad to 512 fp8). Pipeline:
//   pack_all (W8/A8 fp8 pre-swizzled, Whh MX frags, bias, Wcls)
//   -> gemm_xg (MX K=128 fp8, pair-contiguous X2)
//   -> lstm_recur (128 wg; MX K=128; 1 output/lane)  [r22, proven 243us]
//   -> crf3_k (emission GEMM fused into CRF scan; E in LDS) -> fin_k

typedef unsigned short u16;
typedef __attribute__((ext_vector_type(8))) __bf16 bf16x8;
typedef __attribute__((ext_vector_type(4))) float f32x4;
typedef __attribute__((ext_vector_type(8))) int i32x8;
typedef __attribute__((ext_vector_type(4))) int i32x4;

struct __align__(8) u16x4 { u16 x, y, z, w; };

typedef const void __attribute__((address_space(1))) gas_t;
typedef void __attribute__((address_space(3))) las_t;

static __device__ __forceinline__ void gload16(const void* g, void* l) {
  __builtin_amdgcn_global_load_lds((gas_t*)g, (las_t*)l, 16, 0, 0);
}

static __device__ __forceinline__ u16 f2b(float x) {
  uint32_t u = __builtin_bit_cast(uint32_t, x);
  uint32_t r = u + 0x7fffu + ((u >> 16) & 1u);
  return (u16)(r >> 16);
}
static __device__ __forceinline__ float b2lo(uint32_t u) {
  return __builtin_bit_cast(float, u << 16);
}
static __device__ __forceinline__ float b2hi(uint32_t u) {
  return __builtin_bit_cast(float, u & 0xffff0000u);
}
static __device__ __forceinline__ uint32_t pkbf16(float lo, float hi) {
  uint32_t w;
  asm("v_cvt_pk_bf16_f32 %0, %1, %2" : "=v"(w) : "v"(lo), "v"(hi));
  return w;
}
static __device__ __forceinline__ uint32_t pkf8x4(float x, float y, float z, float w) {
  unsigned int r01 = __builtin_amdgcn_cvt_pk_fp8_f32(x, y, 0u, false) & 0xffffu;
  unsigned int r23 = __builtin_amdgcn_cvt_pk_fp8_f32(z, w, 0u, false) & 0xffffu;
  return r01 | (r23 << 16);
}
static __device__ __forceinline__ float sigf(float x) {
  return __builtin_amdgcn_rcpf(1.f + __expf(-x));
}
static __device__ __forceinline__ float tanh_(float x) {
  return 1.f - 2.f * __builtin_amdgcn_rcpf(1.f + __expf(2.f * x));
}
static __device__ __forceinline__ f32x4 MFMA(bf16x8 a, bf16x8 b, f32x4 c) {
  return __builtin_amdgcn_mfma_f32_16x16x32_bf16(a, b, c, 0, 0, 0);
}

// ---------------- pack_all ----------------
// W8 [2048][512] fp8, swizzled c^=(r&7)<<4; bias 2048 f32; WclsP [48][512] bf16;
// WhhF8 MX frags (131072 dwords, r20 layout); A8 [32768][512] fp8, swizzled.
__global__ __launch_bounds__(256) void pack_all(
    const float* __restrict__ Wih_f, const float* __restrict__ Wih_b,
    const float* __restrict__ Whh_f, const float* __restrict__ Whh_b,
    const float* __restrict__ bih_f, const float* __restrict__ bhh_f,
    const float* __restrict__ bih_b, const float* __restrict__ bhh_b,
    const float* __restrict__ Wcls,
    const int* __restrict__ data, const int* __restrict__ onerad,
    const float* __restrict__ embed, const float* __restrict__ rad,
    unsigned char* __restrict__ W8, unsigned int* __restrict__ WhhF8,
    float* __restrict__ biasP, u16* __restrict__ WclsP,
    unsigned char* __restrict__ A8) {
  if (blockIdx.x < 1640) {
    int idx = blockIdx.x * 256 + threadIdx.x;
    if (idx < 262144) {                       // W8: 2048 rows x 128 chunks
      int r = idx >> 7, c7 = idx & 127, k0 = c7 * 4;
      int d = r >> 10, rr = r & 1023;
      const float* W = d ? Wih_b : Wih_f;
      float4 f;
      if (k0 < 428) f = *(const float4*)(W + (size_t)rr * 428 + k0);
      else          f = make_float4(0.f, 0.f, 0.f, 0.f);
      *(unsigned int*)(W8 + (size_t)r * 512 + (k0 ^ ((r & 7) << 4))) =
          pkf8x4(f.x, f.y, f.z, f.w);
    } else if (idx < 264192) {                // bias 2048
      int j = idx - 262144;
      int r = j & 1023;
      biasP[j] = (j >> 10) ? (bih_b[r] + bhh_b[r]) : (bih_f[r] + bhh_f[r]);
    } else if (idx < 288768) {                // Wcls 48*512
      int j = idx - 264192;
      int r = j >> 9, k = j & 511;
      WclsP[j] = (r < 33) ? f2b(Wcls[r * 512 + k]) : (u16)0;
    } else if (idx < 419840) {                // WhhF8: 131072 dwords (MX frags)
      int q = idx - 288768;
      int f = q >> 9;                 // frag 0..255
      int kt = f & 1, u = (f >> 1) & 7, v = (f >> 4) & 7, dd = f >> 7;
      int w9 = q & 511;
      int lane = w9 >> 3;
      int eb = (w9 & 7) * 4;
      int gate = u >> 1, jf = u & 1;
      int gcol = gate * 256 + v * 32 + jf * 16 + (lane & 15);
      int k = kt * 128 + (lane >> 4) * 32 + eb;
      const float* W = dd ? Whh_b : Whh_f;
      float4 fv4 = *(const float4*)(W + (size_t)gcol * 256 + k);
      WhhF8[q] = pkf8x4(fv4.x, fv4.y, fv4.z, fv4.w);
    }
  } else {
    int idx = (blockIdx.x - 1640) * 256 + threadIdx.x;  // 32768*128 chunks
    int m = idx >> 7, c = idx & 127, k0 = c * 4;
    float4 vv;
    if (k0 < 128)      vv = *(const float4*)(embed + (size_t)data[m] * 128 + k0);
    else if (k0 < 228) vv = *(const float4*)(rad + (size_t)onerad[m] * 100 + (k0 - 128));
    else if (k0 < 328) vv = *(const float4*)(rad + (size_t)onerad[32768 + m] * 100 + (k0 - 228));
    else if (k0 < 428) vv = *(const float4*)(rad + (size_t)onerad[65536 + m] * 100 + (k0 - 328));
    else               vv = make_float4(0.f, 0.f, 0.f, 0.f);
    *(unsigned int*)(A8 + (size_t)m * 512 + (k0 ^ ((m & 7) << 4))) =
        pkf8x4(vv.x, vv.y, vv.z, vv.w);
  }
}

// ---------------- xg GEMM (MX fp8): X2 = pair-contiguous(A @ Wih^T + bias) ----------------
// 128x128 tile, BK=128, 4 waves (2x2 of 64x64), 64 mfma_scale_16x16x128/wave.
// Staging: o = ps*4096 + tid*16 (LDS dest wave-uniform + lane*16).
// X2 u16 layout per d (33554432 u16): idx = R*1024 + gate*256 + v*32 + l16*2 + jf.
#define GXM(i, j) \
  acc[i][j] = __builtin_amdgcn_mfma_scale_f32_16x16x128_f8f6f4( \
      af[i], bfj, acc[i][j], 0, 0, 0, 0x7F7F7F7Fu, 0, 0x7F7F7F7Fu);
__global__ __launch_bounds__(256, 2) void gemm_xg(const unsigned char* __restrict__ A8,
    const unsigned char* __restrict__ W8, const float* __restrict__ bias,
    u16* __restrict__ X2) {
  __shared__ unsigned char As[16384];   // [128][128]
  __shared__ unsigned char Bs[16384];
  int bid = blockIdx.x;
  int mt = bid >> 4, nt = bid & 15;
  int m0 = mt * 128, n0 = nt * 128;
  int tid = threadIdx.x;
  int w = tid >> 6, lane = tid & 63, l16 = lane & 15;
  int wr = w >> 1, wc = w & 1;
  int kc0 = (lane >> 4) * 32;
  f32x4 zero4 = {0.f, 0.f, 0.f, 0.f};
  f32x4 acc[4][4];
#pragma unroll
  for (int i = 0; i < 4; ++i)
#pragma unroll
    for (int j = 0; j < 4; ++j) acc[i][j] = zero4;
  for (int kk = 0; kk < 4; ++kk) {
    int kb = kk * 128;
#pragma unroll
    for (int ps = 0; ps < 4; ++ps) {
      int o = ps * 4096 + tid * 16;       // LDS dest: wave-uniform + lane*16
      int rs = o >> 7, cb = o & 127;      // global src: per-lane
      gload16(A8 + (size_t)(m0 + rs) * 512 + kb + cb, (char*)As + o);
      gload16(W8 + (size_t)(n0 + rs) * 512 + kb + cb, (char*)Bs + o);
    }
    __syncthreads();
    i32x8 af[4];
#pragma unroll
    for (int i = 0; i < 4; ++i) {
      int arow = wr * 64 + i * 16 + l16;
      int sw = (arow & 7) << 4;
      const unsigned char* ab = As + arow * 128;
      i32x4 x0 = *(const i32x4*)(ab + (kc0 ^ sw));
      i32x4 x1 = *(const i32x4*)(ab + ((kc0 + 16) ^ sw));
      af[i] = (i32x8){x0[0], x0[1], x0[2], x0[3], x1[0], x1[1], x1[2], x1[3]};
    }
#pragma unroll
    for (int j = 0; j < 4; ++j) {
      int brow = wc * 64 + j * 16 + l16;
      int sw = (brow & 7) << 4;
      const unsigned char* bb = Bs + brow * 128;
      i32x4 y0 = *(const i32x4*)(bb + (kc0 ^ sw));
      i32x4 y1 = *(const i32x4*)(bb + ((kc0 + 16) ^ sw));
      i32x8 bfj = (i32x8){y0[0], y0[1], y0[2], y0[3], y1[0], y1[1], y1[2], y1[3]};
      GXM(0, j) GXM(1, j) GXM(2, j) GXM(3, j)
    }
    __syncthreads();
  }
  float bv[4];
#pragma unroll
  for (int j = 0; j < 4; ++j) bv[j] = bias[n0 + wc * 64 + j * 16 + l16];
  int dd = n0 >> 10;
  int g = lane >> 4;
#pragma unroll
  for (int i = 0; i < 4; ++i)
#pragma unroll
    for (int jp = 0; jp < 2; ++jp) {
      int j0 = jp * 2;
      int c = (n0 + wc * 64 + j0 * 16 + l16) & 1023;   // jf=0 member
      int gate = c >> 8, vv = (c >> 5) & 7, lc = c & 15;
      size_t base = (size_t)dd * 33554432 + (size_t)gate * 256 + vv * 32 + lc * 2;
#pragma unroll
      for (int r = 0; r < 4; ++r) {
        int row = m0 + wr * 64 + i * 16 + g * 4 + r;
        *(unsigned int*)(X2 + base + (size_t)row * 1024) =
            pkbf16(acc[i][j0][r] + bv[j0], acc[i][j0 + 1][r] + bv[j0 + 1]);
      }
    }
}

// ---------------- LSTM recurrence: 128 blocks, 2-row chunks, MX K=128 MFMA ----------------
// r22, proven 243us (setprio removed -- r23 showed it costs ~14us in lockstep).
// Wave v owns gate-cols {gate*256+v*32+jf*16+[0,16)} (u = gate*2+jf, 8 tiles),
// K=256 as 2 x K=128 scaled MFMAs per tile -> 16 MFMA/wave/step. Whh in 16
// i32x8 register frags. h in LDS [16][256] fp8 XOR-swizzled; lane owns ONE
// output (row = lane>>5, col = v*32+jf*16+l16).
#define MXM(u, Af, Bf) \
  acc[u] = __builtin_amdgcn_mfma_scale_f32_16x16x128_f8f6f4( \
      Af, Bf, acc[u], 0, 0, 0, 0x7F7F7F7Fu, 0, 0x7F7F7F7Fu);
#define GVAL(gate, dst) { \
  float a00 = __shfl(acc[(gate) * 2][0],     srcl); \
  float a01 = __shfl(acc[(gate) * 2][1],     srcl); \
  float a10 = __shfl(acc[(gate) * 2 + 1][0], srcl); \
  float a11 = __shfl(acc[(gate) * 2 + 1][1], srcl); \
  float s0 = hirow ? a01 : a00; \
  float s1 = hirow ? a11 : a10; \
  float xv = hijf ? b2hi(pxA[gate]) : b2lo(pxA[gate]); \
  dst = (hijf ? s1 : s0) + xv; }
#define FENCE { __builtin_amdgcn_sched_barrier(0); \
  asm volatile("s_waitcnt lgkmcnt(0)"); \
  __builtin_amdgcn_s_barrier(); \
  __builtin_amdgcn_sched_barrier(0); }

__global__ __launch_bounds__(512, 1) void lstm_recur(const u16* __restrict__ xg,
    const unsigned char* __restrict__ WhhF8, u16* __restrict__ outh) {
  __shared__ unsigned char hfA[2][4096];   // [16 rows][256 k] fp8, XOR-swizzled
  int blk = blockIdx.x;
  int d = blk >> 6, ch = blk & 63;
  int rowA0 = ch * 2;
  int tid = threadIdx.x;
  int v = tid >> 6, lane = tid & 63, l16 = lane & 15;
  int row = lane >> 5;           // output row 0/1
  int jf = (lane >> 4) & 1;
  bool hirow = (row == 1), hijf = (jf == 1);
  int srcl = l16;
  int col = v * 32 + jf * 16 + l16;

  const char* wb = (const char*)WhhF8 + (size_t)(d * 8 + v) * 32768 + (size_t)lane * 32;
  i32x8 bf0  = *(const i32x8*)(wb);
  i32x8 bf1  = *(const i32x8*)(wb + 2048);
  i32x8 bf2  = *(const i32x8*)(wb + 4096);
  i32x8 bf3  = *(const i32x8*)(wb + 6144);
  i32x8 bf4  = *(const i32x8*)(wb + 8192);
  i32x8 bf5  = *(const i32x8*)(wb + 10240);
  i32x8 bf6  = *(const i32x8*)(wb + 12288);
  i32x8 bf7  = *(const i32x8*)(wb + 14336);
  i32x8 bf8  = *(const i32x8*)(wb + 16384);
  i32x8 bf9  = *(const i32x8*)(wb + 18432);
  i32x8 bf10 = *(const i32x8*)(wb + 20480);
  i32x8 bf11 = *(const i32x8*)(wb + 22528);
  i32x8 bf12 = *(const i32x8*)(wb + 24576);
  i32x8 bf13 = *(const i32x8*)(wb + 26624);
  i32x8 bf14 = *(const i32x8*)(wb + 28672);
  i32x8 bf15 = *(const i32x8*)(wb + 30720);
  asm volatile("" :: "v"(bf0), "v"(bf1), "v"(bf2), "v"(bf3), "v"(bf4),
               "v"(bf5), "v"(bf6), "v"(bf7), "v"(bf8), "v"(bf9), "v"(bf10),
               "v"(bf11), "v"(bf12), "v"(bf13), "v"(bf14), "v"(bf15));

  for (int i = tid; i < 2048; i += 512) ((int*)hfA)[i] = 0;

  int arow = lane & 15;
  int sw = (arow & 7) << 4;
  int kb = (lane >> 4) * 32;
  int o0 = arow * 256 + ((kb) ^ sw);
  int o1 = arow * 256 + ((kb + 16) ^ sw);
  int o2 = arow * 256 + ((kb + 128) ^ sw);
  int o3 = arow * 256 + ((kb + 144) ^ sw);

  int t0 = d ? 255 : 0;
  int tpx = d ? -2048 : 2048;    // bytes per t-step in X2 (1024 u16/row-step)
  int tob = d ? -1024 : 1024;    // bytes per t-step in outh (512 u16)

  const char* pb = (const char*)xg + (size_t)d * 67108864
      + ((size_t)(rowA0 + row) * 256 + t0) * 2048 + v * 64 + l16 * 4;
  char* sb = (char*)outh
      + (((size_t)(rowA0 + row) * 256 + t0) * 512 + d * 256 + col) * 2;
  int fwoff = row * 256 + (col ^ (row << 4));   // row&7 == row (0/1)

  unsigned int pxA[4];
  pxA[0] = *(const unsigned int*)(pb);
  pxA[1] = *(const unsigned int*)(pb + 512);
  pxA[2] = *(const unsigned int*)(pb + 1024);
  pxA[3] = *(const unsigned int*)(pb + 1536);

  asm volatile("s_waitcnt vmcnt(0)" ::: "memory");
  __builtin_amdgcn_sched_barrier(0);

  f32x4 zero4 = {0.f, 0.f, 0.f, 0.f};
  float cst = 0.f;
  f32x4 acc[8];
  __syncthreads();

#pragma unroll 1
  for (int tt = 0; tt < 256; ++tt) {
    int p = tt & 1;
    {
      const unsigned char* hb = &hfA[p][0];
      i32x4 a0 = *(const i32x4*)(hb + o0);
      i32x4 a1 = *(const i32x4*)(hb + o1);
      i32x4 a2 = *(const i32x4*)(hb + o2);
      i32x4 a3 = *(const i32x4*)(hb + o3);
      asm volatile("s_waitcnt lgkmcnt(0)");
      __builtin_amdgcn_sched_barrier(0);
      i32x8 A0 = {a0[0], a0[1], a0[2], a0[3], a1[0], a1[1], a1[2], a1[3]};
      i32x8 A1 = {a2[0], a2[1], a2[2], a2[3], a3[0], a3[1], a3[2], a3[3]};
      acc[0] = zero4; acc[1] = zero4; acc[2] = zero4; acc[3] = zero4;
      acc[4] = zero4; acc[5] = zero4; acc[6] = zero4; acc[7] = zero4;
      MXM(0, A0, bf0)  MXM(1, A0, bf2)  MXM(2, A0, bf4)  MXM(3, A0, bf6)
      MXM(4, A0, bf8)  MXM(5, A0, bf10) MXM(6, A0, bf12) MXM(7, A0, bf14)
      MXM(0, A1, bf1)  MXM(1, A1, bf3)  MXM(2, A1, bf5)  MXM(3, A1, bf7)
      MXM(4, A1, bf9)  MXM(5, A1, bf11) MXM(6, A1, bf13) MXM(7, A1, bf15)
    }
    {
      float iv, fv, gv, ov;
      GVAL(0, iv) GVAL(1, fv) GVAL(2, gv) GVAL(3, ov)
      float cn = sigf(fv) * cst + sigf(iv) * tanh_(gv);
      cst = cn;
      float hv = sigf(ov) * tanh_(cn);
      hfA[p ^ 1][fwoff] =
          (unsigned char)__builtin_amdgcn_cvt_pk_fp8_f32(hv, hv, 0u, false);
      *(u16*)sb = f2b(hv);
    }
    sb += tob; pb += tpx;
    pxA[0] = *(const unsigned int*)(pb);
    pxA[1] = *(const unsigned int*)(pb + 512);
    pxA[2] = *(const unsigned int*)(pb + 1024);
    pxA[3] = *(const unsigned int*)(pb + 1536);
    FENCE;
  }
}

// ---------------- crf3: emission GEMM + golden + CRF scan, fused ----------------
// 128 blocks x 256 thr. Phase 1: E[256][33] = outh_rows @ Wcls^T + bcls via
// bf16 MFMA (4 waves x 64 rows each), written straight to LDS. Phase 2:
// wave 0 computes golden + forward logsumexp scan (all threads hit barriers).
__global__ __launch_bounds__(256) void crf3_k(const int* __restrict__ tag,
    const u16* __restrict__ outh, const u16* __restrict__ WclsP,
    const float* __restrict__ bcls, const float* __restrict__ T,
    float* __restrict__ part) {
  __shared__ float Ts[1089];
  __shared__ float E[8448];
  __shared__ float sc[33];
  __shared__ int   lenS;
  __shared__ float gS;
  int b = blockIdx.x;
  int tid = threadIdx.x;
  int w = tid >> 6, lane = tid & 63, l16 = lane & 15, g = lane >> 4;
  for (int i = tid; i < 1089; i += 256) Ts[i] = T[i];
  // ---- emission GEMM into E ----
  {
    f32x4 zero4 = {0.f, 0.f, 0.f, 0.f};
    f32x4 acc[4][3];
#pragma unroll
    for (int mf = 0; mf < 4; ++mf)
#pragma unroll
      for (int nf = 0; nf < 3; ++nf) acc[mf][nf] = zero4;
    int mbase = b * 256 + w * 64;
#pragma unroll 1
    for (int kf = 0; kf < 16; ++kf) {
      bf16x8 bb[3];
#pragma unroll
      for (int nf = 0; nf < 3; ++nf)
        bb[nf] = *(const bf16x8*)(WclsP + (size_t)(nf * 16 + l16) * 512 + kf * 32 + g * 8);
#pragma unroll
      for (int mf = 0; mf < 4; ++mf) {
        bf16x8 a = *(const bf16x8*)(outh
            + (size_t)(mbase + mf * 16 + l16) * 512 + kf * 32 + g * 8);
#pragma unroll
        for (int nf = 0; nf < 3; ++nf) acc[mf][nf] = MFMA(a, bb[nf], acc[mf][nf]);
      }
    }
#pragma unroll
    for (int nf = 0; nf < 3; ++nf) {
      int c = nf * 16 + l16;
      if (c < 33) {
        float bc = bcls[c];
#pragma unroll
        for (int mf = 0; mf < 4; ++mf)
#pragma unroll
          for (int r = 0; r < 4; ++r)
            E[(w * 64 + mf * 16 + g * 4 + r) * 33 + c] = acc[mf][nf][r] + bc;
      }
    }
  }
  // ---- len (wave 0) ----
  if (w == 0) {
    int cnt = 0;
    for (int i = lane; i < 256; i += 64) cnt += (tag[b * 256 + i] != 0) ? 1 : 0;
#pragma unroll
    for (int o = 1; o < 64; o <<= 1) cnt += __shfl_xor(cnt, o);
    if (lane == 0) lenS = cnt;
  }
  __syncthreads();   // E + Ts + lenS visible
  if (w == 0) {
    float gval = 0.f;
    for (int l = lane; l < 256; l += 64) {
      int tg = tag[b * 256 + l];
      if (tg != 0) {
        int prev = (l == 0) ? 31 : tag[b * 256 + l - 1];
        gval += E[l * 33 + tg] + Ts[prev * 33 + tg];
      }
    }
#pragma unroll
    for (int o = 32; o > 0; o >>= 1) gval += __shfl_down(gval, o);
    if (lane == 0) gS = gval;
  }
  // ---- forward scan (all threads participate in barriers) ----
  int c = tid;
  float tcol[33];
  if (c < 33) {
#pragma unroll
    for (int p = 0; p < 33; ++p) tcol[p] = Ts[p * 33 + c];
    sc[c] = E[c] + tcol[31];   // START=31
  }
  __syncthreads();
  int len = lenS;
#pragma unroll 1
  for (int t = 1; t < len; ++t) {
    float nv = 0.f;
    if (c < 33) {
      float ec = E[t * 33 + c];
      float vb[33];
      float m0 = -3.0e38f, m1 = -3.0e38f, m2 = -3.0e38f, m3 = -3.0e38f;
#pragma unroll
      for (int p = 0; p < 32; p += 4) {
        vb[p]     = sc[p]     + tcol[p];     m0 = fmaxf(m0, vb[p]);
        vb[p + 1] = sc[p + 1] + tcol[p + 1]; m1 = fmaxf(m1, vb[p + 1]);
        vb[p + 2] = sc[p + 2] + tcol[p + 2]; m2 = fmaxf(m2, vb[p + 2]);
        vb[p + 3] = sc[p + 3] + tcol[p + 3]; m3 = fmaxf(m3, vb[p + 3]);
      }
      vb[32] = sc[32] + tcol[32];
      float mx = fmaxf(fmaxf(fmaxf(m0, m1), fmaxf(m2, m3)), vb[32]);
      float s0 = 0.f, s1 = 0.f, s2 = 0.f, s3 = 0.f;
#pragma unroll
      for (int p = 0; p < 32; p += 4) {
        s0 += __expf(vb[p] - mx);     s1 += __expf(vb[p + 1] - mx);
        s2 += __expf(vb[p + 2] - mx); s3 += __expf(vb[p + 3] - mx);
      }
      s0 += __expf(vb[32] - mx);
      nv = ec + mx + __logf((s0 + s1) + (s2 + s3));
    }
    __syncthreads();
    if (c < 33) sc[c] = nv;
    __syncthreads();
  }
  if (tid == 0) part[b] = sc[32] - gS;   // END=32
}

// ---------------- finalize: loss = sum(part) / 128 ----------------
__global__ __launch_bounds__(64) void fin_k(const float* __restrict__ part,
    float* __restrict__ out) {
  int l = threadIdx.x;
  float v = part[l] + part[l + 64];
#pragma unroll
  for (int o = 32; o > 0; o >>= 1) v += __shfl_down(v, o);
  if (l == 0) out[0] = v / 128.f;
}

extern "C" void kernel_launch(void* const* d_in, const int* in_sizes, int n_in,
                              void* d_out, int out_size, void* d_ws, size_t ws_size,
                              hipStream_t stream) {
  const int*   batch_data   = (const int*)d_in[0];
  const int*   batch_onerad = (const int*)d_in[1];
  const int*   batch_tag    = (const int*)d_in[2];
  const float* embed        = (const float*)d_in[3];
  const float* rad_embed    = (const float*)d_in[4];
  const float* Wih_f = (const float*)d_in[5];
  const float* Whh_f = (const float*)d_in[6];
  const float* bih_f = (const float*)d_in[7];
  const float* bhh_f = (const float*)d_in[8];
  const float* Wih_b = (const float*)d_in[9];
  const float* Whh_b = (const float*)d_in[10];
  const float* bih_b = (const float*)d_in[11];
  const float* bhh_b = (const float*)d_in[12];
  const float* Wcls  = (const float*)d_in[13];
  const float* bcls  = (const float*)d_in[14];
  const float* trans = (const float*)d_in[15];

  // workspace layout (~203.9 MB)
  char* ws = (char*)d_ws;
  unsigned char* A8 = (unsigned char*)(ws + 0);  // 32768*512 = 16777216
  u16*   X2    = (u16*)  (ws + 29360128);     // 134217728 (pair-contiguous xg)
  unsigned char* W8 = (unsigned char*)(ws + 163577856);  // 2048*512 = 1048576
  unsigned int* WhhF8 = (unsigned int*)(ws + 165412864); // 524288 (MX frags)
  float* biasP = (float*)(ws + 165937152);    // 8192
  u16*   WclsP = (u16*)  (ws + 165945344);    // 49152
  u16*   outh  = (u16*)  (ws + 165994496);    // 33554432
  float* part  = (float*)(ws + 203874304);    // 512

  pack_all<<<18024, 256, 0, stream>>>(Wih_f, Wih_b, Whh_f, Whh_b, bih_f, bhh_f,
                                      bih_b, bhh_b, Wcls, batch_data, batch_onerad,
                                      embed, rad_embed, W8, WhhF8, biasP, WclsP, A8);
  gemm_xg<<<4096, 256, 0, stream>>>(A8, W8, biasP, X2);
  lstm_recur<<<128, 512, 0, stream>>>(X2, (const unsigned char*)WhhF8, outh);
  crf3_k<<<128, 256, 0, stream>>>(batch_tag, outh, WclsP, bcls, trans, part);
  fin_k<<<1, 64, 0, stream>>>(part, (float*)d_out);
}